// Round 3
// baseline (110.098 us; speedup 1.0000x reference)
//
#include <hip/hip_runtime.h>

// CIN fused 3-layer, bf16 MFMA (R9): swapped-operand, register-streamed W.
// cur[sl,n] = sum_f x_f[sl] * S_f[sl,n],  S_f = sum_g h_g[sl] * W[f*64+g, n].
//
// R8 post-mortem: LDS-instruction bound (192 ds_read_b128/phase/CU ~ 2300 cy
// vs 2570 cy measured phase time). MfmaUtil*dur invariant ~12.5 us = MFMA floor.
//
// R9: compute cur^T via mfma(A=W^T-frag, B=h-frag):
//  - h (layer-resident) lives in the B operand -> hoisted to VGPRs per layer,
//    ZERO per-f LDS reads for it.
//  - W (streamed) is the A operand, global->VGPR dwordx4, depth-4 modulo
//    schedule, no LDS staging, no K-loop barriers. Each CU reads the 16 KB
//    tile exactly once per f (8 n-waves x disjoint coalesced 1 KB).
//  - C layout (col=lane&15) puts sl on c -> x_f[sl] is a per-lane SCALAR;
//    xT[sl][f] (stride 44) gives one b128 per 4 f's per sl-tile.
//  - 16 waves = 8 n-tiles x 2 f-halves (f-split keeps 4 waves/SIMD without
//    doubling L2 demand); partial cur summed via 32 KB LDS once per layer.
//  - f padded to 40/layer (tile f==39 is zeros; x pad col is zero) so both
//    halves run exactly 20 iters; prefetch clamped to last tile.
//
// wt layout (prep output), tile tl = l*40+f:
//   wt[tl*8192 + ((ks*128 + n)*4 + q)*8 + j] = bf16(W_l[f*64 + ks*32+q*8+j][n])
// lane (q,c) of n-wave wn reads A-frag W[g=ks*32+q*8+j][n=wn*16+c]:
//   16B at tl*8192 + ks*4096 + ((wn*16+c)*4+q)*8  -> wave = contiguous 1 KB.

#define NF      39
#define LCH     128
#define NLAYER  3
#define LSTR    40                  // padded tiles per layer (f==39 zero tile)
#define NTILES  (NLAYER * LSTR)     // 120
#define TILE_SH 8192                // shorts per tile (16 KB)
#define SLN     64                  // slices per block (4 batches x 16 d)
#define XPAD    44                  // xT row stride (16B-aligned, 2-way banks)
#define FHALF   20                  // f-iters per half

typedef __bf16        bf16x8 __attribute__((ext_vector_type(8)));
typedef unsigned int  uint4v __attribute__((ext_vector_type(4)));
typedef float         f32x4  __attribute__((ext_vector_type(4)));

__device__ __forceinline__ unsigned short f2bf_rne(float f) {
    unsigned u = __float_as_uint(f);
    u += 0x7fffu + ((u >> 16) & 1u);
    return (unsigned short)(u >> 16);
}

// ---------------- prep: W fp32 -> bf16 frag-ready transposed tiles ----------
__global__ void cin_prep(const float* __restrict__ W0,
                         const float* __restrict__ W1,
                         const float* __restrict__ W2,
                         unsigned short* __restrict__ wt)
{
    const int t = blockIdx.x * blockDim.x + threadIdx.x; // tl*1024 + ks*512 + n*4 + q
    if (t >= NTILES * 1024) return;
    const int q  = t & 3;
    const int n  = (t >> 2) & 127;
    const int ks = (t >> 9) & 1;
    const int tl = t >> 10;
    const int l  = tl / LSTR;
    const int f  = tl - l * LSTR;
    const float* W = (l == 0) ? W0 : (l == 1) ? W1 : W2;

    unsigned short v[8];
    #pragma unroll
    for (int j = 0; j < 8; ++j) {
        const int g = ks * 32 + q * 8 + j;
        float w = 0.0f;
        if (f < NF) {
            if (l == 0) { if (g < NF) w = W[(f * NF + g) * LCH + n]; }
            else        { w = W[(f * 64 + g) * LCH + n]; }
        }
        v[j] = f2bf_rne(w);
    }
    uint4v pv;
    #pragma unroll
    for (int i = 0; i < 4; ++i)
        pv[i] = (unsigned)v[2 * i] | ((unsigned)v[2 * i + 1] << 16);
    ((uint4v*)wt)[t] = pv;   // 16B coalesced
}

// ---------------- main ----------------
__global__ __launch_bounds__(1024, 4) void cin_mfma(
    const float* __restrict__ x,
    const unsigned short* __restrict__ wt,
    const float* __restrict__ b0p,
    const float* __restrict__ b1p,
    const float* __restrict__ b2p,
    float* __restrict__ out)
{
    __shared__ __align__(16) unsigned short hfrag[8 * SLN * 8]; // 8 KB
    __shared__ __align__(16) float xT[SLN * XPAD];              // 11.3 KB [sl][f]
    __shared__ float biasl[NLAYER * LCH];                       // 1.5 KB
    __shared__ __align__(16) float rbuf[8 * 64 * 16];           // 32 KB f-half exch

    const int tid  = threadIdx.x;
    const int lane = tid & 63;
    const int w    = tid >> 6;      // wave 0..15
    const int wn   = w & 7;         // n-tile
    const int fh   = w >> 3;        // f-half
    const int q    = lane >> 4;
    const int c    = lane & 15;
    const int nc   = wn * 16 + c;
    const int bb   = blockIdx.x * 4;
    const int fb   = fh * FHALF;    // 0 or 20

    // zero hfrag (layer-0 padding g in [39,64)); zero xT pad col f=39
    if (tid < 512) { f32x4 z4 = {0.f,0.f,0.f,0.f}; ((f32x4*)hfrag)[tid] = z4; }
    if (tid < SLN) xT[tid * XPAD + NF] = 0.f;
    if (tid < NLAYER * LCH)
        biasl[tid] = (tid < 128) ? b0p[tid] : (tid < 256) ? b1p[tid-128] : b2p[tid-256];
    __syncthreads();

    // stage x: xT[sl][f] fp32 + hfrag bf16 (layer-0 h)
    for (int i = tid; i < 4 * NF * 16; i += 1024) {
        const float v = x[bb * (NF * 16) + i];
        const int lb = i / (NF * 16);
        const int r  = i - lb * (NF * 16);
        const int f  = r >> 4;
        const int d  = r & 15;
        const int sl = lb * 16 + d;
        xT[sl * XPAD + f] = v;
        hfrag[((f >> 3) * SLN + sl) * 8 + (f & 7)] = f2bf_rne(v);
    }
    __syncthreads();

    // per-lane W-frag base (A-operand), ks=1 at +4096 shorts
    const unsigned short* wqp = wt + (nc * 4 + q) * 8;

    #pragma unroll 1
    for (int l = 0; l < NLAYER; ++l) {
        // hoist h B-frags for this layer: lane (q,c) holds h[g=q*8+j(+32*ks)][sl=st*16+c]
        bf16x8 h0[4], h1[4];
        #pragma unroll
        for (int st = 0; st < 4; ++st) {
            h0[st] = *(const bf16x8*)&hfrag[(( q    ) * SLN + st * 16 + c) * 8];
            h1[st] = *(const bf16x8*)&hfrag[((4 + q) * SLN + st * 16 + c) * 8];
        }

        // prime depth-4 W slots: tiles l*40+fb+{0..3}
        const unsigned short* wl = wqp + (size_t)(l * LSTR + fb) * TILE_SH;
        bf16x8 s0a = *(const bf16x8*)(wl);
        bf16x8 s0b = *(const bf16x8*)(wl + 4096);
        bf16x8 s1a = *(const bf16x8*)(wl + TILE_SH);
        bf16x8 s1b = *(const bf16x8*)(wl + TILE_SH + 4096);
        bf16x8 s2a = *(const bf16x8*)(wl + 2 * TILE_SH);
        bf16x8 s2b = *(const bf16x8*)(wl + 2 * TILE_SH + 4096);
        bf16x8 s3a = *(const bf16x8*)(wl + 3 * TILE_SH);
        bf16x8 s3b = *(const bf16x8*)(wl + 3 * TILE_SH + 4096);

        f32x4 cur0 = {0.f,0.f,0.f,0.f}, cur1 = cur0, cur2 = cur0, cur3 = cur0;
        const f32x4 z = {0.f,0.f,0.f,0.f};

        #pragma unroll 1
        for (int fi4 = 0; fi4 < FHALF; fi4 += 4) {
            const int xo = fb + fi4;
            const f32x4 xq0 = *(const f32x4*)&xT[(0 * 16 + c) * XPAD + xo];
            const f32x4 xq1 = *(const f32x4*)&xT[(1 * 16 + c) * XPAD + xo];
            const f32x4 xq2 = *(const f32x4*)&xT[(2 * 16 + c) * XPAD + xo];
            const f32x4 xq3 = *(const f32x4*)&xT[(3 * 16 + c) * XPAD + xo];

            // modulo-4 schedule: slot J consumed, then reloaded with tile +4
#define SUBIT(J, SA, SB)                                                           \
            {                                                                      \
                f32x4 sv;                                                          \
                sv = __builtin_amdgcn_mfma_f32_16x16x32_bf16(SA, h0[0], z, 0,0,0); \
                sv = __builtin_amdgcn_mfma_f32_16x16x32_bf16(SB, h1[0], sv,0,0,0); \
                cur0 += xq0[J] * sv;                                               \
                sv = __builtin_amdgcn_mfma_f32_16x16x32_bf16(SA, h0[1], z, 0,0,0); \
                sv = __builtin_amdgcn_mfma_f32_16x16x32_bf16(SB, h1[1], sv,0,0,0); \
                cur1 += xq1[J] * sv;                                               \
                sv = __builtin_amdgcn_mfma_f32_16x16x32_bf16(SA, h0[2], z, 0,0,0); \
                sv = __builtin_amdgcn_mfma_f32_16x16x32_bf16(SB, h1[2], sv,0,0,0); \
                cur2 += xq2[J] * sv;                                               \
                sv = __builtin_amdgcn_mfma_f32_16x16x32_bf16(SA, h0[3], z, 0,0,0); \
                sv = __builtin_amdgcn_mfma_f32_16x16x32_bf16(SB, h1[3], sv,0,0,0); \
                cur3 += xq3[J] * sv;                                               \
                int tn = l * LSTR + fb + fi4 + (J) + 4;                            \
                if (tn > NTILES - 1) tn = NTILES - 1;                              \
                const unsigned short* tp = wqp + (size_t)tn * TILE_SH;             \
                SA = *(const bf16x8*)(tp);                                         \
                SB = *(const bf16x8*)(tp + 4096);                                  \
            }
            SUBIT(0, s0a, s0b)
            SUBIT(1, s1a, s1b)
            SUBIT(2, s2a, s2b)
            SUBIT(3, s3a, s3b)
#undef SUBIT
        }

        // ---------------- layer end: f-half reduce + epilogue ----------------
        if (fh == 1) {
            float* rb = &rbuf[(wn * 64 + lane) * 16];
            *(f32x4*)(rb +  0) = cur0;
            *(f32x4*)(rb +  4) = cur1;
            *(f32x4*)(rb +  8) = cur2;
            *(f32x4*)(rb + 12) = cur3;
        }
        __syncthreads();
        if (fh == 0) {
            const float* rb = &rbuf[(wn * 64 + lane) * 16];
            const f32x4 bq = *(const f32x4*)&biasl[l * LCH + wn * 16 + q * 4];
            f32x4 vv0 = cur0 + *(const f32x4*)(rb +  0);
            f32x4 vv1 = cur1 + *(const f32x4*)(rb +  4);
            f32x4 vv2 = cur2 + *(const f32x4*)(rb +  8);
            f32x4 vv3 = cur3 + *(const f32x4*)(rb + 12);
            #pragma unroll
            for (int r = 0; r < 4; ++r) {
                vv0[r] = fmaxf(vv0[r] + bq[r], 0.f);
                vv1[r] = fmaxf(vv1[r] + bq[r], 0.f);
                vv2[r] = fmaxf(vv2[r] + bq[r], 0.f);
                vv3[r] = fmaxf(vv3[r] + bq[r], 0.f);
            }
            if (l < 2 && wn < 4) {
                // h channels (n<64): write next layer's h; lane holds
                // n = wn*16+q*4+r, sl = st*16+c
#define HWR(ST, VV)                                                            \
                _Pragma("unroll")                                              \
                for (int r = 0; r < 4; ++r) {                                  \
                    const int n = wn * 16 + q * 4 + r;                         \
                    hfrag[((n >> 3) * SLN + (ST) * 16 + c) * 8 + (n & 7)] =    \
                        f2bf_rne(VV[r]);                                       \
                }
                HWR(0, vv0) HWR(1, vv1) HWR(2, vv2) HWR(3, vv3)
#undef HWR
            } else {
                // direct: reduce over d (= c lanes) and store
#define DST(ST, VV)                                                            \
                _Pragma("unroll")                                              \
                for (int r = 0; r < 4; ++r) {                                  \
                    float s = VV[r];                                           \
                    s += __shfl_xor(s, 1, 64);                                 \
                    s += __shfl_xor(s, 2, 64);                                 \
                    s += __shfl_xor(s, 4, 64);                                 \
                    s += __shfl_xor(s, 8, 64);                                 \
                    if (c == 0) {                                              \
                        const int n = wn * 16 + q * 4 + r;                     \
                        const int outcol = (l == 0) ? n - 64                   \
                                         : (l == 1) ? n : 128 + n;             \
                        out[(bb + (ST)) * 256 + outcol] = s;                   \
                    }                                                          \
                }
                DST(0, vv0) DST(1, vv1) DST(2, vv2) DST(3, vv3)
#undef DST
            }
        }
        if (l < 2) __syncthreads();   // h writes visible before next hoist
    }
}

extern "C" void kernel_launch(void* const* d_in, const int* in_sizes, int n_in,
                              void* d_out, int out_size, void* d_ws, size_t ws_size,
                              hipStream_t stream) {
    const float* x  = (const float*)d_in[0];
    const float* W0 = (const float*)d_in[1];
    const float* W1 = (const float*)d_in[2];
    const float* W2 = (const float*)d_in[3];
    const float* b0 = (const float*)d_in[4];
    const float* b1 = (const float*)d_in[5];
    const float* b2 = (const float*)d_in[6];
    float* out = (float*)d_out;
    unsigned short* wt = (unsigned short*)d_ws;  // 120*8192*2 B = 1.97 MB

    const int prep_threads = NTILES * 1024;      // 122880
    cin_prep<<<(prep_threads + 255) / 256, 256, 0, stream>>>(W0, W1, W2, wt);
    cin_mfma<<<256, 1024, 0, stream>>>(x, wt, b0, b1, b2, out);
}